// Round 16
// baseline (99.644 us; speedup 1.0000x reference)
//
#include <hip/hip_runtime.h>

#define BB 8
#define TT 256
#define UU 64
#define VV 512
#define U1 (UU + 1)
#define NK 8                    // chunk slots per batch
#define CH 32                   // max steps per chunk
#define MS 66                   // M row stride (65 + pad)

#define LOG2E 1.4426950408889634f
#define LN2   0.6931471805599453f
#define NEG   (-1e30f)
#define NEG_INF (-__builtin_inff())

typedef float floatx4 __attribute__((ext_vector_type(4)));

__device__ __forceinline__ float vexp2(float x) {
    float r; asm("v_exp_f32 %0, %1" : "=v"(r) : "v"(x)); return r;
}
__device__ __forceinline__ float vlog2(float x) {
    float r; asm("v_log_f32 %0, %1" : "=v"(r) : "v"(x)); return r;
}
__device__ __forceinline__ float negabs(float x) {
    return __int_as_float(__float_as_int(x) | 0x80000000u);
}
__device__ __forceinline__ float rdlane63(float x) {
    return __int_as_float(__builtin_amdgcn_readlane(__float_as_int(x), 63));
}

template<int CTRL, int RMASK>
__device__ __forceinline__ float dpp_mov(float v, float oldv) {
    int r = __builtin_amdgcn_update_dpp(__float_as_int(oldv), __float_as_int(v),
                                        CTRL, RMASK, 0xf, false);
    return __int_as_float(r);
}

__device__ __forceinline__ float wave_addscan(float v) {
    v += dpp_mov<0x111, 0xf>(v, 0.f);
    v += dpp_mov<0x112, 0xf>(v, 0.f);
    v += dpp_mov<0x114, 0xf>(v, 0.f);
    v += dpp_mov<0x118, 0xf>(v, 0.f);
    v += dpp_mov<0x142, 0xa>(v, 0.f);
    v += dpp_mov<0x143, 0xc>(v, 0.f);
    return v;
}
__device__ __forceinline__ float wave_maxscan(float v) {
    v = fmaxf(v, dpp_mov<0x111, 0xf>(v, NEG_INF));
    v = fmaxf(v, dpp_mov<0x112, 0xf>(v, NEG_INF));
    v = fmaxf(v, dpp_mov<0x114, 0xf>(v, NEG_INF));
    v = fmaxf(v, dpp_mov<0x118, 0xf>(v, NEG_INF));
    v = fmaxf(v, dpp_mov<0x142, 0xa>(v, NEG_INF));
    v = fmaxf(v, dpp_mov<0x143, 0xc>(v, NEG_INF));
    return v;
}

// plain 2-way logadd, log2 domain
__device__ __forceinline__ float logadd2(float a, float b) {
    float m = fmaxf(a, b);
    return m + vlog2(1.0f + vexp2(negabs(a - b)));
}

// One g-domain recursion step (verbatim round 8, verified absmax=0).
__device__ __forceinline__ void scan_step(float r, float z, float& am, float& as,
                                          float& a64m, float& a64s) {
    float f0 = am + r;
    float p1 = dpp_mov<0x111, 0xf>(f0, NEG_INF); float m1 = fmaxf(f0, p1);
    float p2 = dpp_mov<0x112, 0xf>(m1, NEG_INF); float m2 = fmaxf(m1, p2);
    float p3 = dpp_mov<0x114, 0xf>(m2, NEG_INF); float m3 = fmaxf(m2, p3);
    float p4 = dpp_mov<0x118, 0xf>(m3, NEG_INF); float m4 = fmaxf(m3, p4);
    float p5 = dpp_mov<0x142, 0xa>(m4, NEG_INF); float m5 = fmaxf(m4, p5);
    float p6 = dpp_mov<0x143, 0xc>(m5, NEG_INF); float m6 = fmaxf(m5, p6);
    float e1 = vexp2(negabs(f0 - p1));
    float e2 = vexp2(negabs(m1 - p2));
    float e3 = vexp2(negabs(m2 - p3));
    float e4 = vexp2(negabs(m3 - p4));
    float e5 = vexp2(negabs(m4 - p5));
    float e6 = vexp2(negabs(m5 - p6));
    bool c1 = f0 >= p1, c2 = m1 >= p2, c3 = m2 >= p3,
         c4 = m3 >= p4, c5 = m4 >= p5, c6 = m5 >= p6;
    float s_ = as;
    { float ps = dpp_mov<0x111, 0xf>(s_, 0.f); float bg = c1 ? s_ : ps, sm = c1 ? ps : s_; s_ = fmaf(sm, e1, bg); }
    { float ps = dpp_mov<0x112, 0xf>(s_, 0.f); float bg = c2 ? s_ : ps, sm = c2 ? ps : s_; s_ = fmaf(sm, e2, bg); }
    { float ps = dpp_mov<0x114, 0xf>(s_, 0.f); float bg = c3 ? s_ : ps, sm = c3 ? ps : s_; s_ = fmaf(sm, e3, bg); }
    { float ps = dpp_mov<0x118, 0xf>(s_, 0.f); float bg = c4 ? s_ : ps, sm = c4 ? ps : s_; s_ = fmaf(sm, e4, bg); }
    { float ps = dpp_mov<0x142, 0xa>(s_, 0.f); float bg = c5 ? s_ : ps, sm = c5 ? ps : s_; s_ = fmaf(sm, e5, bg); }
    { float ps = dpp_mov<0x143, 0xc>(s_, 0.f); float bg = c6 ? s_ : ps, sm = c6 ? ps : s_; s_ = fmaf(sm, e6, bg); }
    float f64 = a64m + z;
    bool  cc  = f64 >= m6;
    float ee  = vexp2(negabs(f64 - m6));
    float bg = cc ? a64s : s_, sm = cc ? s_ : a64s;
    a64s = fmaf(sm, ee, bg);
    a64m = cc ? f64 : m6;
    am = m6; as = s_;
}

// Kernel 1: per-row log-softmax (verbatim round 8; culled).
__global__ __launch_bounds__(256) void k_logsm(const float* __restrict__ logits,
                                               const int* __restrict__ targets,
                                               const int* __restrict__ loglen,
                                               const int* __restrict__ tgtlen,
                                               float* __restrict__ blank,
                                               float* __restrict__ emit) {
    int wave = (int)((blockIdx.x * blockDim.x + threadIdx.x) >> 6);
    int lane = threadIdx.x & 63;
    const int nrows = BB * TT * U1;
    if (wave >= nrows) return;
    int u  = wave % U1;
    int bt = wave / U1;
    int b  = bt / TT;
    int t  = bt - b * TT;
    if (t >= loglen[b] || u > tgtlen[b]) return;   // dead row

    const float* row = logits + (size_t)wave * VV;
    floatx4 v0 = __builtin_nontemporal_load((const floatx4*)(row + lane * 4));
    floatx4 v1 = __builtin_nontemporal_load((const floatx4*)(row + 256 + lane * 4));
    float m8 = fmaxf(fmaxf(fmaxf(v0.x, v0.y), fmaxf(v0.z, v0.w)),
                     fmaxf(fmaxf(v1.x, v1.y), fmaxf(v1.z, v1.w)));
    float M = rdlane63(wave_maxscan(m8));
    float s8 = __expf(v0.x - M) + __expf(v0.y - M) + __expf(v0.z - M) + __expf(v0.w - M)
             + __expf(v1.x - M) + __expf(v1.y - M) + __expf(v1.z - M) + __expf(v1.w - M);
    float S = rdlane63(wave_addscan(s8));
    float lse = M + __logf(S);

    if (lane == 0) blank[wave] = v0.x - lse;
    if (u < UU) {
        int tgt = targets[b * UU + u];             // in [1, V)
        int owner = (tgt & 255) >> 2;
        if (lane == owner) {
            int slot = tgt & 3;
            float x0 = (tgt < 256) ? v0.x : v1.x;
            float x1 = (tgt < 256) ? v0.y : v1.y;
            float x2 = (tgt < 256) ? v0.z : v1.z;
            float x3 = (tgt < 256) ? v0.w : v1.w;
            float val = (slot == 0) ? x0 : (slot == 1) ? x1 : (slot == 2) ? x2 : x3;
            emit[bt * UU + u] = val - lse;
        }
    }
}

// Kernel 2: build cum2 (exclusive cumsum, LOG2 domain), Dp (plain [b][s][64]
// layout, log2), z64 ([b][s], log2). Zero out[0].
__global__ __launch_bounds__(256) void k_prep(const float* __restrict__ emit,
                                              const float* __restrict__ blank,
                                              const int* __restrict__ loglen,
                                              float* __restrict__ cum2,
                                              float* __restrict__ Dp,
                                              float* __restrict__ z64,
                                              float* __restrict__ out0) {
    int wave = (int)((blockIdx.x * blockDim.x + threadIdx.x) >> 6);
    int l = threadIdx.x & 63;
    if (wave >= BB * TT) return;
    if (wave == 0 && l == 0) out0[0] = 0.f;
    int b = wave >> 8, t = wave & 255;
    if (t >= loglen[b]) return;
    float e = emit[wave * UU + l];
    float incl = wave_addscan(e);
    float excl = incl - e;
    cum2[wave * U1 + l] = excl * LOG2E;
    float inclT63 = rdlane63(incl);
    if (l == 63) cum2[wave * U1 + 64] = incl * LOG2E;
    if (t >= 1) {
        float eP = emit[(wave - 1) * UU + l];
        float inclP = wave_addscan(eP);
        float exclP = inclP - eP;
        float bl = blank[(size_t)(wave - 1) * U1 + l];
        int s = t - 1;
        Dp[(b * 256 + s) * 64 + l] = (bl + exclP - excl) * LOG2E;
        float inclP63 = rdlane63(inclP);
        if (l == 0)
            z64[b * 256 + s] = (blank[(size_t)(wave - 1) * U1 + 64] + inclP63 - inclT63) * LOG2E;
    }
}

// Kernel 3: chunk transfer-matrix columns. One wave per (b, k, v):
// run <=32 steps of the g-domain recursion from unit init at lane v; store
// M[b][k][u][v] = g[u] + cum2[end][u] - cum2[start][v]  (plain log2 floats).
__global__ __launch_bounds__(256) void k_cols(const float* __restrict__ Dp,
                                              const float* __restrict__ z64,
                                              const float* __restrict__ cum2,
                                              const int* __restrict__ loglen,
                                              float* __restrict__ Mm) {
    int w = (int)(blockIdx.x * 4 + (threadIdx.x >> 6));
    int l = threadIdx.x & 63;
    if (w >= BB * NK * U1) return;
    int b = w / (NK * U1);
    int rem = w - b * (NK * U1);
    int k = rem / U1;
    int v = rem - k * U1;
    int t_idx = loglen[b] - 1;
    float* Mcol = Mm + ((size_t)(b * NK + k) * U1 + v) * MS;

    int end = t_idx - CH * (NK - 1 - k);
    int start = end - CH; if (start < 0) start = 0;
    int nst = (end > 0) ? (end - start) : 0;

    if (nst <= 0) {                       // identity column
        Mcol[l] = (l == v) ? 0.f : NEG;
        if (l == 63) Mcol[64] = (v == 64) ? 0.f : NEG;
        return;
    }

    float am = (l == v) ? 0.f : NEG, as = 1.f;
    float a64m = (v == 64) ? 0.f : NEG, a64s = 1.f;

    const float* Db = Dp + (size_t)(b * 256 + start) * 64 + l;
    const float* zb = z64 + b * 256 + start;
    for (int j = 0; j < nst; ++j) {
        float r = Db[j * 64];
        float z = zb[j];
        scan_step(r, z, am, as, a64m, a64s);
        if ((j & 3) == 3) {
            int e1; as = frexpf(as, &e1); am += (float)e1;
            int e2; a64s = frexpf(a64s, &e2); a64m += (float)e2;
        }
    }
    float cS = cum2[(b * 256 + start) * U1 + v];       // uniform (column offset)
    float cE = cum2[(b * 256 + end) * U1 + l];         // per-lane
    Mcol[l] = am + vlog2(as) + cE - cS;
    if (l == 63) {
        float cE64 = cum2[(b * 256 + end) * U1 + 64];
        Mcol[64] = a64m + vlog2(a64s) + cE64 - cS;
    }
}

// Kernel 4: per-batch combine: x = alpha_0 (= cum2 row 0); apply 8 chunk
// matrices in slot order (log-semiring matvec); read out at (t_idx, u_idx).
__global__ __launch_bounds__(64) void k_comb(const float* __restrict__ Mm,
                                             const float* __restrict__ cum2,
                                             const float* __restrict__ blank,
                                             const int* __restrict__ loglen,
                                             const int* __restrict__ tgtlen,
                                             float* __restrict__ out) {
    int b = blockIdx.x;
    int l = threadIdx.x;
    int t_idx = loglen[b] - 1;
    int u_idx = tgtlen[b];

    float x   = cum2[(b * 256) * U1 + l];
    float x64 = cum2[(b * 256) * U1 + 64];

    for (int k = 0; k < NK; ++k) {
        const float* Mk = Mm + ((size_t)(b * NK + k) * U1) * MS;
        // row 64: lane v holds M[64][v] + x[v]; butterfly log-reduce (uniform)
        float t64 = Mk[l * MS + 64] + x;
        #pragma unroll
        for (int off = 1; off < 64; off <<= 1)
            t64 = logadd2(t64, __shfl_xor(t64, off));
        float y64 = logadd2(t64, Mk[64 * MS + 64] + x64);
        // main rows: lane u accumulates over v as (m,s) pair
        float am = NEG, as = 1.f;
        #pragma unroll 8
        for (int v = 0; v < 64; ++v) {
            float tm = Mk[v * MS + l] + __shfl(x, v);
            bool c = am >= tm;
            float wgt = vexp2(negabs(am - tm));
            float bg = c ? as : 1.f, sm = c ? 1.f : as;
            as = fmaf(sm, wgt, bg);
            am = fmaxf(am, tm);
        }
        {   // v = 64 term
            float tm = Mk[64 * MS + l] + x64;
            bool c = am >= tm;
            float wgt = vexp2(negabs(am - tm));
            float bg = c ? as : 1.f, sm = c ? 1.f : as;
            as = fmaf(sm, wgt, bg);
            am = fmaxf(am, tm);
        }
        x = am + vlog2(as);
        x64 = y64;
    }

    bool w64 = (u_idx == 64);
    if ((w64 && l == 0) || (!w64 && l == u_idx)) {
        float a = w64 ? x64 : x;
        float fb = blank[(size_t)(b * 256 + t_idx) * U1 + u_idx];
        atomicAdd(out, -0.125f * (a * LN2 + fb));
    }
}

extern "C" void kernel_launch(void* const* d_in, const int* in_sizes, int n_in,
                              void* d_out, int out_size, void* d_ws, size_t ws_size,
                              hipStream_t stream) {
    const float* logits  = (const float*)d_in[0];
    const int*   targets = (const int*)d_in[1];
    const int*   loglen  = (const int*)d_in[2];
    const int*   tgtlen  = (const int*)d_in[3];

    float* ws    = (float*)d_ws;
    float* blank = ws;                           // 8*256*65 = 133120
    float* emit  = blank + BB * TT * U1;         // 8*256*64 = 131072
    float* cum2  = emit  + BB * TT * UU;         // 133120
    float* Dp    = cum2  + BB * TT * U1;         // 131072
    float* z64   = Dp    + BB * TT * UU;         // 2048
    float* Mm    = z64   + BB * TT;              // 8*8*65*66 = 274560

    const int nrows = BB * TT * U1;
    k_logsm<<<nrows / 4, 256, 0, stream>>>(logits, targets, loglen, tgtlen, blank, emit);
    k_prep<<<(BB * TT) / 4, 256, 0, stream>>>(emit, blank, loglen, cum2, Dp, z64, (float*)d_out);
    k_cols<<<(BB * NK * U1 + 3) / 4, 256, 0, stream>>>(Dp, z64, cum2, loglen, Mm);
    k_comb<<<BB, 64, 0, stream>>>(Mm, cum2, blank, loglen, tgtlen, (float*)d_out);
}